// Round 2
// baseline (343.450 us; speedup 1.0000x reference)
//
#include <hip/hip_runtime.h>
#include <math.h>

#define CB 512
#define CS 1024
#define CT 50
#define PF 4   // x-prefetch depth / renorm cadence

typedef float v2f __attribute__((ext_vector_type(2)));

#if __has_builtin(__builtin_amdgcn_permlane16_swap)
#define HAVE_PL16 1
#else
#define HAVE_PL16 0
#endif
#if __has_builtin(__builtin_amdgcn_permlane32_swap)
#define HAVE_PL32 1
#else
#define HAVE_PL32 0
#endif

__global__ void zero_out_kernel(float* out) { out[0] = 0.0f; }

__device__ __forceinline__ int lane0_bits(float v) {
    return __builtin_amdgcn_readlane(__float_as_int(v), 0);
}

// generic DPP mov: quad_perm 0xB1 = xor1, 0x4E = xor2; row_ror:4 = 0x124, row_ror:8 = 0x128
template <int CTRL>
__device__ __forceinline__ float dppmov(float v) {
    return __int_as_float(__builtin_amdgcn_update_dpp(
        0, __float_as_int(v), CTRL, 0xf, 0xf, false));
}

// pairsum32(a) = a(from lane with bit5=0 of pair) + a(from lane with bit5=1).
// Uses BOTH outputs of permlane32_swap summed -> order/parity agnostic, also
// correct under the ds_bpermute fallback.
__device__ __forceinline__ float pairsum32(float a, int lane) {
#if HAVE_PL32
    (void)lane;
    auto r = __builtin_amdgcn_permlane32_swap(__float_as_uint(a), __float_as_uint(a),
                                              false, false);
    return __uint_as_float(r[0]) + __uint_as_float(r[1]);
#else
    float b = __int_as_float(__builtin_amdgcn_ds_bpermute((lane ^ 32) << 2,
                                                          __float_as_int(a)));
    return a + b;
#endif
}

// pairsum16(a) = sum over the bit4-pair (within the 32-half).
__device__ __forceinline__ float pairsum16(float a, int lane) {
    (void)lane;
#if HAVE_PL16
    auto r = __builtin_amdgcn_permlane16_swap(__float_as_uint(a), __float_as_uint(a),
                                              false, false);
    return __uint_as_float(r[0]) + __uint_as_float(r[1]);
#else
    float b = __int_as_float(__builtin_amdgcn_ds_swizzle(__float_as_int(a), 0x401F)); // xor16
    return a + b;
#endif
}

__global__ __launch_bounds__(128, 1) void crf_scan_kernel(
    const float* __restrict__ scores,    // (B,S,T)
    const int*   __restrict__ tags,      // (B,S)
    const int*   __restrict__ mask,      // (B,S)
    const float* __restrict__ trans,     // (T,T)
    const float* __restrict__ start_tr,  // (T)
    const float* __restrict__ end_tr,    // (T)
    float* __restrict__ out)             // scalar
{
    const int b    = blockIdx.x;
    const int tid  = threadIdx.x;
    const int w    = tid >> 6;           // wave 0 = forward, wave 1 = backward
    const int lane = tid & 63;
    const int xl   = (lane < CT) ? lane : 0;
    const int j    = lane & 15;          // position within 16-row
    const int rowb = lane & 48;          // 16 * row-block index
    const bool sel16 = (lane & 16) != 0;
    const bool sel32 = (lane & 32) != 0;

    __shared__ __attribute__((aligned(16))) float sTrans[CT * CT];
    __shared__ float sA[64];
    __shared__ float sB[64];
    __shared__ float sLZ[2], sN[2];

    for (int k = tid; k < CT * CT; k += 128) sTrans[k] = trans[k];
    __syncthreads();

    // Probe row_ror source-lane offsets at runtime; absorbed into EC so the
    // rotation direction convention cannot cause a correctness bug.
    int d4, d8;
    {
        int p4 = __float_as_int(dppmov<0x124>(__int_as_float(lane)));
        int p8 = __float_as_int(dppmov<0x128>(__int_as_float(lane)));
        d4 = (p4 - lane) & 15;
        d8 = (p8 - lane) & 15;
    }

    // ---- per-lane coefficients for the 4x4 block-matvec step ----
    // Gathered reg G[4a+k] holds state of lane i = rowb | (((j+offs[a])&15) ^ k).
    // Slot Q_r accumulates partial for output y[16r + j] from input block rowb/16.
    // coeff(i,s): fwd = exp(trans[i][s]); bwd = exp(trans[s][i]); pads exactly 0.
    v2f EC01[16], EC23[16];
    {
        const int offs[4] = {0, d4, d8, (d4 + d8) & 15};
        #pragma unroll
        for (int a = 0; a < 4; ++a) {
            #pragma unroll
            for (int k = 0; k < 4; ++k) {
                const int g = 4 * a + k;
                const int i = rowb | (((j + offs[a]) & 15) ^ k);
                float e[4];
                #pragma unroll
                for (int r = 0; r < 4; ++r) {
                    const int s = 16 * r + j;
                    e[r] = (i < CT && s < CT)
                         ? __expf(w == 0 ? sTrans[i * CT + s] : sTrans[s * CT + i])
                         : 0.f;
                }
                EC01[g] = (v2f){e[0], e[1]};
                EC23[g] = (v2f){e[2], e[3]};
            }
        }
    }

    // sequence length (prefix mask)
    const int* mrow = mask + (size_t)b * CS;
    int len = 0;
    for (int t = lane; t < CS; t += 64) len += mrow[t];
    #pragma unroll
    for (int off = 32; off; off >>= 1) len += __shfl_xor(len, off);

    const float* srow = scores + (size_t)b * CS * CT;
    const float* sx   = srow + xl;

    const int tm    = (len - 1) >> 1;
    const int count = (w == 0) ? tm : ((len >= 2) ? (len - 2 - tm) : 0);
    const int base  = (w == 0) ? 1 : (len - 2);
    const int dir   = (w == 0) ? 1 : -1;

    // linear-domain state; pad lanes (state>=50) exactly 0
    float st;
    if (w == 0) {
        st = (lane < CT) ? __expf(start_tr[lane] + sx[0]) : 0.f;
    } else {
        st = (lane < CT)
            ? ((len >= 2) ? __expf(end_tr[lane] + sx[(size_t)(len - 1) * CT])
                          : __expf(end_tr[lane]))
            : 0.f;
    }
    int kexp = 0;

    // One step: intra-row all-gather (fast DPP only), 4x8-deep pk_fma chains,
    // 2-level canonical pair-sum combine (8 heavy cross-lane ops), select, scale.
    #define STEP(EX)                                                        \
    {                                                                       \
        float G[16];                                                        \
        G[0]  = st;                                                         \
        G[1]  = dppmov<0xB1>(st);                                           \
        G[2]  = dppmov<0x4E>(st);                                           \
        G[3]  = dppmov<0x4E>(G[1]);                                         \
        G[4]  = dppmov<0x124>(G[0]);                                        \
        G[5]  = dppmov<0x124>(G[1]);                                        \
        G[6]  = dppmov<0x124>(G[2]);                                        \
        G[7]  = dppmov<0x124>(G[3]);                                        \
        G[8]  = dppmov<0x128>(G[0]);                                        \
        G[9]  = dppmov<0x128>(G[1]);                                        \
        G[10] = dppmov<0x128>(G[2]);                                        \
        G[11] = dppmov<0x128>(G[3]);                                        \
        G[12] = dppmov<0x128>(G[4]);                                        \
        G[13] = dppmov<0x128>(G[5]);                                        \
        G[14] = dppmov<0x128>(G[6]);                                        \
        G[15] = dppmov<0x128>(G[7]);                                        \
        v2f q01a = {0.f,0.f}, q01b = {0.f,0.f};                             \
        v2f q23a = {0.f,0.f}, q23b = {0.f,0.f};                             \
        _Pragma("unroll")                                                   \
        for (int g = 0; g < 8; ++g) {                                       \
            const v2f t2 = {G[g], G[g]};                                    \
            q01a = __builtin_elementwise_fma(t2, EC01[g], q01a);            \
            q23a = __builtin_elementwise_fma(t2, EC23[g], q23a);            \
        }                                                                   \
        _Pragma("unroll")                                                   \
        for (int g = 8; g < 16; ++g) {                                      \
            const v2f t2 = {G[g], G[g]};                                    \
            q01b = __builtin_elementwise_fma(t2, EC01[g], q01b);            \
            q23b = __builtin_elementwise_fma(t2, EC23[g], q23b);            \
        }                                                                   \
        const v2f Q01 = q01a + q01b;                                        \
        const v2f Q23 = q23a + q23b;                                        \
        const float Y0 = pairsum16(pairsum32(Q01.x, lane), lane);           \
        const float Y1 = pairsum16(pairsum32(Q01.y, lane), lane);           \
        const float Y2 = pairsum16(pairsum32(Q23.x, lane), lane);           \
        const float Y3 = pairsum16(pairsum32(Q23.y, lane), lane);           \
        const float u0 = sel16 ? Y1 : Y0;                                   \
        const float u1 = sel16 ? Y3 : Y2;                                   \
        st = (sel32 ? u1 : u0) * (EX);                                      \
    }

    #define RENORM()                                                        \
    {                                                                       \
        int sb = lane0_bits(st);                                            \
        int e  = (sb >> 23) & 0xff;                                         \
        kexp  += e - 127;                                                   \
        st    *= __int_as_float((254 - e) << 23);                           \
    }

    // ---- scan: PF-step chunks, x prefetch, renorm per chunk ----
    float xpf[PF];
    #pragma unroll
    for (int k = 0; k < PF; ++k) {
        int idx = base + dir * k;
        if (idx < 0) idx = 0;
        xpf[k] = sx[(size_t)idx * CT];
    }
    int k = 0;
    while (k + PF <= count) {
        float exk[PF];
        #pragma unroll
        for (int jj = 0; jj < PF; ++jj) exk[jj] = __expf(xpf[jj]);
        #pragma unroll
        for (int jj = 0; jj < PF; ++jj) {
            int idx = base + dir * (k + PF + jj);
            if (idx < 0) idx = 0;
            xpf[jj] = sx[(size_t)idx * CT];
        }
        RENORM();
        STEP(exk[0]); STEP(exk[1]); STEP(exk[2]); STEP(exk[3]);
        k += PF;
    }
    for (int r = 0; k < count; ++k, ++r) {
        float e = __expf(xpf[r]);
        RENORM();
        STEP(e);
    }
    // bwd epilogue: B_tm = E * C_{tm+1} (no exp(x) factor)
    if (w == 1 && len >= 2) { RENORM(); STEP(1.0f); }
    RENORM();
    #undef STEP
    #undef RENORM

    // ---- combine across waves ----
    if (w == 0) sA[lane] = (lane < CT) ? st : 0.0f;
    else        sB[lane] = (lane < CT) ? st : 0.0f;
    if (lane == 0) sLZ[w] = (float)kexp * 0.6931471805599453f;
    __syncthreads();

    // numerator: gold-path score, all 128 threads
    const int* trow = tags + (size_t)b * CS;
    float nsum = 0.0f;
    for (int t = tid; t < CS; t += 128) {
        if (t < len) {
            int tg = trow[t];
            nsum += srow[(size_t)t * CT + tg];
            if (t >= 1) nsum += sTrans[trow[t - 1] * CT + tg];
        }
    }
    #pragma unroll
    for (int off = 32; off; off >>= 1) nsum += __shfl_xor(nsum, off);
    if (lane == 0) sN[w] = nsum;

    float den = 0.0f;
    if (w == 0) {
        float vp = sA[lane] * sB[lane];
        #pragma unroll
        for (int off = 32; off; off >>= 1) vp += __shfl_xor(vp, off);
        den = sLZ[0] + sLZ[1] + __logf(vp);
    }
    __syncthreads();

    if (tid == 0) {
        float num = sN[0] + sN[1] + start_tr[trow[0]] + end_tr[trow[len - 1]];
        atomicAdd(out, (den - num) * (1.0f / CB));
    }
}

extern "C" void kernel_launch(void* const* d_in, const int* in_sizes, int n_in,
                              void* d_out, int out_size, void* d_ws, size_t ws_size,
                              hipStream_t stream) {
    const float* scores   = (const float*)d_in[0];
    const int*   tags     = (const int*)d_in[1];
    const int*   mask     = (const int*)d_in[2];
    const float* trans    = (const float*)d_in[3];
    const float* start_tr = (const float*)d_in[4];
    const float* end_tr   = (const float*)d_in[5];
    float* out = (float*)d_out;

    zero_out_kernel<<<1, 1, 0, stream>>>(out);
    crf_scan_kernel<<<CB, 128, 0, stream>>>(scores, tags, mask, trans,
                                            start_tr, end_tr, out);
}

// Round 3
// 305.985 us; speedup vs baseline: 1.1224x; 1.1224x over previous
//
#include <hip/hip_runtime.h>
#include <math.h>

#define CB 512
#define CS 1024
#define CT 50
#define PF 4   // x-prefetch depth / exp batch

typedef float v2f __attribute__((ext_vector_type(2)));

__global__ void zero_out_kernel(float* out) { out[0] = 0.0f; }

// Compiler-level fence only — same-wave DS ops complete in order on CDNA.
__device__ __forceinline__ void wave_fence() {
    __builtin_amdgcn_wave_barrier();
    asm volatile("" ::: "memory");
}

__device__ __forceinline__ int lane0_bits(float v) {
    return __builtin_amdgcn_readlane(__float_as_int(v), 0);
}

// quad_perm DPP move (VALU pipe, no DS): ctrl 0xB1 = xor1, 0x4E = xor2
template <int CTRL>
__device__ __forceinline__ float qperm(float v) {
    return __int_as_float(__builtin_amdgcn_update_dpp(
        0, __float_as_int(v), CTRL, 0xf, 0xf, false));
}

__global__ __launch_bounds__(128, 1) void crf_scan_kernel(
    const float* __restrict__ scores,    // (B,S,T)
    const int*   __restrict__ tags,      // (B,S)
    const int*   __restrict__ mask,      // (B,S)
    const float* __restrict__ trans,     // (T,T)
    const float* __restrict__ start_tr,  // (T)
    const float* __restrict__ end_tr,    // (T)
    float* __restrict__ out)             // scalar
{
    const int b    = blockIdx.x;
    const int tid  = threadIdx.x;
    const int w    = tid >> 6;           // wave 0 = forward, wave 1 = backward
    const int lane = tid & 63;
    const int xl   = (lane < CT) ? lane : 0;
    const int g    = lane & 3;           // i-quarter this lane accumulates
    const int m    = lane >> 2;          // quad index; lane owns state == lane
    const bool selb0 = (lane & 1) != 0;
    const bool selb1 = (lane & 2) != 0;

    __shared__ __attribute__((aligned(16))) float sTrans[CT * CT];
    __shared__ __attribute__((aligned(16))) float sP2[2][2][64]; // [wave][buf][state]
    __shared__ __attribute__((aligned(16))) float sA[64];
    __shared__ __attribute__((aligned(16))) float sB[64];
    __shared__ float sLZ[2], sN[2];

    for (int k = tid; k < CT * CT; k += 128) sTrans[k] = trans[k];
    __syncthreads();

    // E fragments: lane covers i in [16g, 16g+16), states s = 4m+c, c<4.
    // fwd (w=0): coeff(i,s) = exp(trans[i][s]); bwd (w=1): coeff(i,s) = exp(trans[s][i]).
    // Pads (i>=50 or s>=50) are exactly 0 so pad states stay 0 forever.
    v2f EC0[16], EC1[16];
    {
        const int i0 = 16 * g, s0 = 4 * m;
        #pragma unroll
        for (int k = 0; k < 16; ++k) {
            const int i = i0 + k;
            float e[4] = {0.f, 0.f, 0.f, 0.f};
            if (i < CT) {
                #pragma unroll
                for (int c = 0; c < 4; ++c) {
                    const int s = s0 + c;
                    if (s < CT)
                        e[c] = __expf(w == 0 ? sTrans[i * CT + s]
                                             : sTrans[s * CT + i]);
                }
            }
            EC0[k] = (v2f){e[0], e[1]};
            EC1[k] = (v2f){e[2], e[3]};
        }
    }

    // sequence length (prefix mask)
    const int* mrow = mask + (size_t)b * CS;
    int len = 0;
    for (int t = lane; t < CS; t += 64) len += mrow[t];
    #pragma unroll
    for (int off = 32; off; off >>= 1) len += __shfl_xor(len, off);

    const float* srow = scores + (size_t)b * CS * CT;
    const float* sx   = srow + xl;

    const int tm    = (len - 1) >> 1;
    const int count = (w == 0) ? tm : ((len >= 2) ? (len - 2 - tm) : 0);
    const int base  = (w == 0) ? 1 : (len - 2);
    const int dir   = (w == 0) ? 1 : -1;

    // linear-domain state; pad lanes (state>=50) exactly 0
    float st;
    if (w == 0) {
        st = (lane < CT) ? __expf(start_tr[lane] + sx[0]) : 0.f;
    } else {
        st = (lane < CT)
            ? ((len >= 2) ? __expf(end_tr[lane] + sx[(size_t)(len - 1) * CT])
                          : __expf(end_tr[lane]))
            : 0.f;
    }
    int kexp  = 0;
    int e_obs = (lane0_bits(st) >> 23) & 0xff;   // stale-renorm seed

    // double-buffered broadcast slots (per wave)
    float*        wbuf0 = &sP2[w][0][lane];
    float*        wbuf1 = &sP2[w][1][lane];
    const float4* rbuf0 = (const float4*)&sP2[w][0][16 * g];
    const float4* rbuf1 = (const float4*)&sP2[w][1][16 * g];

    #define T2(V) ((v2f){(V), (V)})
    #define MACF(A0, A1, V, K)                                              \
        A0 = __builtin_elementwise_fma(T2(V), EC0[K], A0);                  \
        A1 = __builtin_elementwise_fma(T2(V), EC1[K], A1);

    // One step: broadcast via LDS (1 write + 4 b128 reads, double-buffered),
    // 4x4-deep FMA tree, quad_perm DPP combine, scale, select.
    #define STEP(WPTR, RPTR, EXS)                                           \
    {                                                                       \
        *(WPTR) = st;                                                       \
        wave_fence();                                                       \
        const float4 p0 = (RPTR)[0];                                        \
        const float4 p1 = (RPTR)[1];                                        \
        const float4 p2 = (RPTR)[2];                                        \
        const float4 p3 = (RPTR)[3];                                        \
        wave_fence(); /* WAR: reads ordered before this buffer's reuse */   \
        v2f A00 = T2(p0.x) * EC0[0],  A10 = T2(p0.x) * EC1[0];              \
        v2f A01 = T2(p1.x) * EC0[4],  A11 = T2(p1.x) * EC1[4];              \
        v2f A02 = T2(p2.x) * EC0[8],  A12 = T2(p2.x) * EC1[8];              \
        v2f A03 = T2(p3.x) * EC0[12], A13 = T2(p3.x) * EC1[12];             \
        MACF(A00, A10, p0.y, 1)  MACF(A00, A10, p0.z, 2)                    \
        MACF(A00, A10, p0.w, 3)                                             \
        MACF(A01, A11, p1.y, 5)  MACF(A01, A11, p1.z, 6)                    \
        MACF(A01, A11, p1.w, 7)                                             \
        MACF(A02, A12, p2.y, 9)  MACF(A02, A12, p2.z, 10)                   \
        MACF(A02, A12, p2.w, 11)                                            \
        MACF(A03, A13, p3.y, 13) MACF(A03, A13, p3.z, 14)                   \
        MACF(A03, A13, p3.w, 15)                                            \
        v2f a0 = (A00 + A01) + (A02 + A03);                                 \
        v2f a1 = (A10 + A11) + (A12 + A13);                                 \
        a0.x += qperm<0xB1>(a0.x); a0.y += qperm<0xB1>(a0.y);               \
        a1.x += qperm<0xB1>(a1.x); a1.y += qperm<0xB1>(a1.y);               \
        a0.x += qperm<0x4E>(a0.x); a0.y += qperm<0x4E>(a0.y);               \
        a1.x += qperm<0x4E>(a1.x); a1.y += qperm<0x4E>(a1.y);               \
        a0 = a0 * T2(EXS);                                                  \
        a1 = a1 * T2(EXS);                                                  \
        const float o01 = selb0 ? a0.y : a0.x;                              \
        const float o23 = selb0 ? a1.y : a1.x;                              \
        st = selb1 ? o23 : o01;                                             \
    }

    // Scaled step: renorm factor comes from the PREVIOUS step's exponent —
    // readlane + scalar ops run during this step's LDS stall, off the chain.
    // Power-of-2 scaling is exact; kexp records every applied scale.
    #define SSTEP(WPTR, RPTR, EX)                                           \
    {                                                                       \
        const float sc_ = __int_as_float((254 - e_obs) << 23);              \
        kexp += e_obs - 127;                                                \
        STEP(WPTR, RPTR, (EX) * sc_);                                       \
        e_obs = (lane0_bits(st) >> 23) & 0xff;                              \
    }

    // ---- scan: PF-step chunks, x prefetch, per-step hidden renorm ----
    float xpf[PF];
    #pragma unroll
    for (int k = 0; k < PF; ++k) {
        int idx = base + dir * k;
        if (idx < 0) idx = 0;
        xpf[k] = sx[(size_t)idx * CT];
    }
    int k = 0;
    while (k + PF <= count) {
        float exk[PF];
        #pragma unroll
        for (int j = 0; j < PF; ++j) exk[j] = __expf(xpf[j]);
        #pragma unroll
        for (int j = 0; j < PF; ++j) {
            int idx = base + dir * (k + PF + j);
            if (idx < 0) idx = 0;
            xpf[j] = sx[(size_t)idx * CT];
        }
        SSTEP(wbuf0, rbuf0, exk[0]);
        SSTEP(wbuf1, rbuf1, exk[1]);
        SSTEP(wbuf0, rbuf0, exk[2]);
        SSTEP(wbuf1, rbuf1, exk[3]);
        k += PF;
    }
    {
        const int rem = count - k;   // 0..PF-1
        if (rem >= 1) { float e = __expf(xpf[0]); SSTEP(wbuf0, rbuf0, e); }
        if (rem >= 2) { float e = __expf(xpf[1]); SSTEP(wbuf1, rbuf1, e); }
        if (rem >= 3) { float e = __expf(xpf[2]); SSTEP(wbuf0, rbuf0, e); }
        // bwd epilogue: B_tm = E * C_{tm+1} (no exp(x) factor)
        if (w == 1 && len >= 2) {
            if (rem & 1) { SSTEP(wbuf1, rbuf1, 1.0f); }
            else         { SSTEP(wbuf0, rbuf0, 1.0f); }
        }
    }
    #undef STEP
    #undef SSTEP
    #undef MACF
    #undef T2

    // ---- combine across waves ----
    if (w == 0) sA[lane] = (lane < CT) ? st : 0.0f;
    else        sB[lane] = (lane < CT) ? st : 0.0f;
    if (lane == 0) sLZ[w] = (float)kexp * 0.6931471805599453f;
    __syncthreads();

    // numerator: gold-path score, all 128 threads
    const int* trow = tags + (size_t)b * CS;
    float nsum = 0.0f;
    for (int t = tid; t < CS; t += 128) {
        if (t < len) {
            int tg = trow[t];
            nsum += srow[(size_t)t * CT + tg];
            if (t >= 1) nsum += sTrans[trow[t - 1] * CT + tg];
        }
    }
    #pragma unroll
    for (int off = 32; off; off >>= 1) nsum += __shfl_xor(nsum, off);
    if (lane == 0) sN[w] = nsum;

    float den = 0.0f;
    if (w == 0) {
        float vp = sA[lane] * sB[lane];
        #pragma unroll
        for (int off = 32; off; off >>= 1) vp += __shfl_xor(vp, off);
        den = sLZ[0] + sLZ[1] + __logf(vp);
    }
    __syncthreads();

    if (tid == 0) {
        float num = sN[0] + sN[1] + start_tr[trow[0]] + end_tr[trow[len - 1]];
        atomicAdd(out, (den - num) * (1.0f / CB));
    }
}

extern "C" void kernel_launch(void* const* d_in, const int* in_sizes, int n_in,
                              void* d_out, int out_size, void* d_ws, size_t ws_size,
                              hipStream_t stream) {
    const float* scores   = (const float*)d_in[0];
    const int*   tags     = (const int*)d_in[1];
    const int*   mask     = (const int*)d_in[2];
    const float* trans    = (const float*)d_in[3];
    const float* start_tr = (const float*)d_in[4];
    const float* end_tr   = (const float*)d_in[5];
    float* out = (float*)d_out;

    zero_out_kernel<<<1, 1, 0, stream>>>(out);
    crf_scan_kernel<<<CB, 128, 0, stream>>>(scores, tags, mask, trans,
                                            start_tr, end_tr, out);
}

// Round 5
// 259.638 us; speedup vs baseline: 1.3228x; 1.1785x over previous
//
#include <hip/hip_runtime.h>
#include <math.h>

#define CB 512
#define CS 1024
#define CT 50
#define PF 4   // x-prefetch depth / renorm cadence

typedef float v2f __attribute__((ext_vector_type(2)));

__global__ void zero_out_kernel(float* out) { out[0] = 0.0f; }

// Compiler-level fence only — same-wave DS ops complete in order on CDNA.
__device__ __forceinline__ void wave_fence() {
    __builtin_amdgcn_wave_barrier();
    asm volatile("" ::: "memory");
}

__device__ __forceinline__ int lane0_bits(float v) {
    return __builtin_amdgcn_readlane(__float_as_int(v), 0);
}

// quad_perm DPP move (VALU pipe, no DS): ctrl 0xB1 = xor1, 0x4E = xor2
template <int CTRL>
__device__ __forceinline__ float qperm(float v) {
    return __int_as_float(__builtin_amdgcn_update_dpp(
        0, __float_as_int(v), CTRL, 0xf, 0xf, false));
}

__global__ __launch_bounds__(128, 1) void crf_scan_kernel(
    const float* __restrict__ scores,    // (B,S,T)
    const int*   __restrict__ tags,      // (B,S)
    const int*   __restrict__ mask,      // (B,S)
    const float* __restrict__ trans,     // (T,T)
    const float* __restrict__ start_tr,  // (T)
    const float* __restrict__ end_tr,    // (T)
    float* __restrict__ out)             // scalar
{
    const int b    = blockIdx.x;
    const int tid  = threadIdx.x;
    const int w    = tid >> 6;           // wave 0 = forward, wave 1 = backward
    const int lane = tid & 63;
    const int xl   = (lane < CT) ? lane : 0;
    const int g    = lane & 3;           // i-quarter this lane accumulates
    const int m    = lane >> 2;          // quad index; lane owns state == lane
    const bool selb0 = (lane & 1) != 0;
    const bool selb1 = (lane & 2) != 0;

    __shared__ __attribute__((aligned(16))) float sTrans[CT * CT];
    __shared__ __attribute__((aligned(16))) float sP2[2][2][64]; // [wave][buf][state]
    __shared__ __attribute__((aligned(16))) float sA[64];
    __shared__ __attribute__((aligned(16))) float sB[64];
    __shared__ float sLZ[2], sN[2];

    for (int k = tid; k < CT * CT; k += 128) sTrans[k] = trans[k];
    __syncthreads();

    // E fragments: lane covers i in [16g, 16g+16), states s = 4m+c, c<4.
    // fwd (w=0): coeff(i,s) = exp(trans[i][s]); bwd (w=1): coeff(i,s) = exp(trans[s][i]).
    // Pads (i>=50 or s>=50) are exactly 0 so pad states stay 0 forever.
    v2f EC0[16], EC1[16];
    {
        const int i0 = 16 * g, s0 = 4 * m;
        #pragma unroll
        for (int k = 0; k < 16; ++k) {
            const int i = i0 + k;
            float e[4] = {0.f, 0.f, 0.f, 0.f};
            if (i < CT) {
                #pragma unroll
                for (int c = 0; c < 4; ++c) {
                    const int s = s0 + c;
                    if (s < CT)
                        e[c] = __expf(w == 0 ? sTrans[i * CT + s]
                                             : sTrans[s * CT + i]);
                }
            }
            EC0[k] = (v2f){e[0], e[1]};
            EC1[k] = (v2f){e[2], e[3]};
        }
    }

    // sequence length (prefix mask)
    const int* mrow = mask + (size_t)b * CS;
    int len = 0;
    for (int t = lane; t < CS; t += 64) len += mrow[t];
    #pragma unroll
    for (int off = 32; off; off >>= 1) len += __shfl_xor(len, off);

    const float* srow = scores + (size_t)b * CS * CT;
    const float* sx   = srow + xl;

    const int tm    = (len - 1) >> 1;
    const int count = (w == 0) ? tm : ((len >= 2) ? (len - 2 - tm) : 0);
    const int base  = (w == 0) ? 1 : (len - 2);
    const int dir   = (w == 0) ? 1 : -1;

    // linear-domain state; pad lanes (state>=50) exactly 0
    float st;
    if (w == 0) {
        st = (lane < CT) ? __expf(start_tr[lane] + sx[0]) : 0.f;
    } else {
        st = (lane < CT)
            ? ((len >= 2) ? __expf(end_tr[lane] + sx[(size_t)(len - 1) * CT])
                          : __expf(end_tr[lane]))
            : 0.f;
    }
    int   kexp = 0;
    float rsc  = 1.0f;

    // double-buffered broadcast slots (per wave)
    float*        wbuf0 = &sP2[w][0][lane];
    float*        wbuf1 = &sP2[w][1][lane];
    const float4* rbuf0 = (const float4*)&sP2[w][0][16 * g];
    const float4* rbuf1 = (const float4*)&sP2[w][1][16 * g];

    // One step: broadcast state via LDS (1 write + 4 b128 reads, double-buffered),
    // 16-deep IN-READ-ORDER FMA chain (hides read latency under lgkmcnt staging),
    // quad_perm DPP combine, select own state, scale by EX (renorm pre-folded).
    #define STEP(WPTR, RPTR, EX)                                            \
    {                                                                       \
        *(WPTR) = st;                                                       \
        wave_fence();                                                       \
        const float4 p0 = (RPTR)[0];                                        \
        const float4 p1 = (RPTR)[1];                                        \
        const float4 p2 = (RPTR)[2];                                        \
        const float4 p3 = (RPTR)[3];                                        \
        wave_fence(); /* WAR: reads ordered before this buffer's reuse */   \
        float pv[16] = {p0.x,p0.y,p0.z,p0.w, p1.x,p1.y,p1.z,p1.w,           \
                        p2.x,p2.y,p2.z,p2.w, p3.x,p3.y,p3.z,p3.w};          \
        v2f a0 = {0.f,0.f}, a1 = {0.f,0.f};                                 \
        _Pragma("unroll")                                                   \
        for (int kk = 0; kk < 16; ++kk) {                                   \
            const v2f t2 = {pv[kk], pv[kk]};                                \
            a0 = __builtin_elementwise_fma(t2, EC0[kk], a0);                \
            a1 = __builtin_elementwise_fma(t2, EC1[kk], a1);                \
        }                                                                   \
        a0.x += qperm<0xB1>(a0.x); a0.y += qperm<0xB1>(a0.y);               \
        a1.x += qperm<0xB1>(a1.x); a1.y += qperm<0xB1>(a1.y);               \
        a0.x += qperm<0x4E>(a0.x); a0.y += qperm<0x4E>(a0.y);               \
        a1.x += qperm<0x4E>(a1.x); a1.y += qperm<0x4E>(a1.y);               \
        const float o01 = selb0 ? a0.y : a0.x;                              \
        const float o23 = selb0 ? a1.y : a1.x;                              \
        st = (selb1 ? o23 : o01) * (EX);                                    \
    }

    // Renorm: read lane0 exponent of st (parallel to the broadcast; does NOT
    // touch st, so the ds_write launches immediately). Scale 2^(127-e) is
    // applied through the next step's EX (linear, power-of-2 exact).
    #define RENORM()                                                        \
    {                                                                       \
        int sb = lane0_bits(st);                                            \
        int e  = (sb >> 23) & 0xff;                                         \
        kexp  += e - 127;                                                   \
        rsc    = __int_as_float((254 - e) << 23);                           \
    }

    // ---- scan: PF-step chunks, x prefetch, renorm folded into EX ----
    float xpf[PF];
    #pragma unroll
    for (int k = 0; k < PF; ++k) {
        int idx = base + dir * k;
        if (idx < 0) idx = 0;
        xpf[k] = sx[(size_t)idx * CT];
    }
    int k = 0;
    while (k + PF <= count) {
        float exk[PF];
        #pragma unroll
        for (int j = 0; j < PF; ++j) exk[j] = __expf(xpf[j]);
        #pragma unroll
        for (int j = 0; j < PF; ++j) {
            int idx = base + dir * (k + PF + j);
            if (idx < 0) idx = 0;
            xpf[j] = sx[(size_t)idx * CT];
        }
        RENORM();
        STEP(wbuf0, rbuf0, exk[0] * rsc);
        STEP(wbuf1, rbuf1, exk[1]);
        STEP(wbuf0, rbuf0, exk[2]);
        STEP(wbuf1, rbuf1, exk[3]);
        k += PF;
    }
    {
        const int rem = count - k;   // 0..PF-1
        if (rem >= 1) { float e = __expf(xpf[0]); RENORM(); STEP(wbuf0, rbuf0, e * rsc); }
        if (rem >= 2) { float e = __expf(xpf[1]); RENORM(); STEP(wbuf1, rbuf1, e * rsc); }
        if (rem >= 3) { float e = __expf(xpf[2]); RENORM(); STEP(wbuf0, rbuf0, e * rsc); }
        // bwd epilogue: B_tm = E * C_{tm+1} (no exp(x) factor)
        if (w == 1 && len >= 2) {
            RENORM();
            if (rem & 1) { STEP(wbuf1, rbuf1, rsc); }
            else         { STEP(wbuf0, rbuf0, rsc); }
        }
    }
    RENORM();
    st *= rsc;
    #undef STEP
    #undef RENORM

    // ---- combine across waves ----
    if (w == 0) sA[lane] = (lane < CT) ? st : 0.0f;
    else        sB[lane] = (lane < CT) ? st : 0.0f;
    if (lane == 0) sLZ[w] = (float)kexp * 0.6931471805599453f;
    __syncthreads();

    // numerator: gold-path score, all 128 threads
    const int* trow = tags + (size_t)b * CS;
    float nsum = 0.0f;
    for (int t = tid; t < CS; t += 128) {
        if (t < len) {
            int tg = trow[t];
            nsum += srow[(size_t)t * CT + tg];
            if (t >= 1) nsum += sTrans[trow[t - 1] * CT + tg];
        }
    }
    #pragma unroll
    for (int off = 32; off; off >>= 1) nsum += __shfl_xor(nsum, off);
    if (lane == 0) sN[w] = nsum;

    float den = 0.0f;
    if (w == 0) {
        float vp = sA[lane] * sB[lane];
        #pragma unroll
        for (int off = 32; off; off >>= 1) vp += __shfl_xor(vp, off);
        den = sLZ[0] + sLZ[1] + __logf(vp);
    }
    __syncthreads();

    if (tid == 0) {
        float num = sN[0] + sN[1] + start_tr[trow[0]] + end_tr[trow[len - 1]];
        atomicAdd(out, (den - num) * (1.0f / CB));
    }
}

extern "C" void kernel_launch(void* const* d_in, const int* in_sizes, int n_in,
                              void* d_out, int out_size, void* d_ws, size_t ws_size,
                              hipStream_t stream) {
    const float* scores   = (const float*)d_in[0];
    const int*   tags     = (const int*)d_in[1];
    const int*   mask     = (const int*)d_in[2];
    const float* trans    = (const float*)d_in[3];
    const float* start_tr = (const float*)d_in[4];
    const float* end_tr   = (const float*)d_in[5];
    float* out = (float*)d_out;

    zero_out_kernel<<<1, 1, 0, stream>>>(out);
    crf_scan_kernel<<<CB, 128, 0, stream>>>(scores, tags, mask, trans,
                                            start_tr, end_tr, out);
}